// Round 16
// baseline (180.692 us; speedup 1.0000x reference)
//
#include <hip/hip_runtime.h>

#define BATCH 4096
#define NI 128
#define NH 256
#define NO 128
#define NG 17
#define GM_ROWS 8
#define K0 2176   // NI*NG
#define KU 1088   // K0/2 uints per basis row

static constexpr size_t EDGE_OFF  = (size_t)BATCH * NO;                    // 524288
static constexpr size_t BASIS_OFF = EDGE_OFF + (size_t)BATCH * NH * NO;    // 134742016
static constexpr size_t SCAL_OFF  = BASIS_OFF + (size_t)BATCH * NH * NG;   // 152567808

typedef float  vf2 __attribute__((ext_vector_type(2)));
typedef float  vf4 __attribute__((ext_vector_type(4)));
typedef short  bf16x8 __attribute__((ext_vector_type(8)));
typedef float  f32x4 __attribute__((ext_vector_type(4)));

__device__ __forceinline__ unsigned short f2bf(float v) {
    unsigned int b = __float_as_uint(v);
    b += 0x7FFFu + ((b >> 16) & 1u);
    return (unsigned short)(b >> 16);
}
__device__ __forceinline__ float4 bf4_to_f4(uint2 v) {
    float4 r;
    r.x = __uint_as_float(v.x << 16);
    r.y = __uint_as_float(v.x & 0xFFFF0000u);
    r.z = __uint_as_float(v.y << 16);
    r.w = __uint_as_float(v.y & 0xFFFF0000u);
    return r;
}

// degree-1 hat-spline taps at grid linspace(-2.5,2.5,17), spacing 0.3125
__device__ __forceinline__ void taps(float v, float& sil, float& wlo, float& whi,
                                     int& glo, int& ghi, float& u) {
    sil = v / (1.0f + __expf(-v));
    u   = (v + 2.5f) * 3.2f;
    float kf = floorf(u);
    int   k  = (int)kf;
    float f  = u - kf;
    wlo = 1.0f - f;  whi = f;
    glo = k;         ghi = k + 1;
    if (glo < 0 || glo > 16) { glo = 0; wlo = 0.0f; }
    if (ghi < 0 || ghi > 16) { ghi = 0; whi = 0.0f; }
}

// ---- prep (single launch, 3 independent parts by block range) ----
// part 1 [0,2372):    w0 -> w0B (r14-verified fragment layout), w1 -> w1t, bs1 -> bs1b
// part 2 [2372,6468): basisA[b][k] = hat(u[b][i(k)], g(k)) in bf16 (row-major K0)
// part 3 [6468,6980): hbase = silu(x) @ bs0  (fp32, 8-row weight sharing)
__global__ __launch_bounds__(256) void prep_all(
    const float* __restrict__ x,
    const float* __restrict__ w0, const float* __restrict__ w1,
    const float* __restrict__ bs1, const float* __restrict__ bs0,
    unsigned short* __restrict__ w0B, unsigned short* __restrict__ w1t,
    unsigned short* __restrict__ bs1b,
    unsigned int* __restrict__ basisA, float* __restrict__ hbase)
{
    __shared__ float s_u[NI];
    __shared__ float s_sil[GM_ROWS * NI];
    const int blk = blockIdx.x;
    const int tid = threadIdx.x;

    if (blk < 2372) {
        int j = blk * 256 + tid;
        const int n0 = 68 * NH;           // 17408
        const int total1 = NH * NG * NO;  // 557056
        if (j < n0) {
            const int kt = j >> 8;        // 0..67
            const int o  = j & 255;
            unsigned short* dst = w0B + (size_t)kt * 8192 + o * 32;
            #pragma unroll
            for (int kl = 0; kl < 32; ++kl) {
                unsigned int k = kt * 32 + kl;
                unsigned int i = (k * 3856u) >> 16;     // k/17 for k<2304
                unsigned int g = k - 17u * i;
                dst[kl] = f2bf(w0[((size_t)i * NH + o) * NG + g]);
            }
        } else if (j < n0 + total1) {
            int jj = j - n0;
            int i = jj / (NG * NO);
            int r = jj - i * (NG * NO);
            int g = r / NO;
            int o = r - g * NO;
            w1t[jj] = f2bf(w1[((size_t)i * NO + o) * NG + g]);
        } else if (j < n0 + total1 + NH * NO) {
            int jj = j - n0 - total1;     // 0..32767
            bs1b[jj] = f2bf(bs1[jj]);
        }
    } else if (blk < 2372 + BATCH) {
        const int b = blk - 2372;
        if (tid < NI) {
            float xv = x[(size_t)b * NI + tid];
            s_u[tid] = (xv + 2.5f) * 3.2f;
        }
        __syncthreads();
        unsigned int* dst = basisA + (size_t)b * KU;
        #pragma unroll
        for (int c = 0; c < 5; ++c) {
            int idx = c * 256 + tid;
            if (idx < KU) {
                unsigned int k0 = idx * 2u, k1 = idx * 2u + 1u;
                unsigned int i0 = (k0 * 3856u) >> 16, g0 = k0 - 17u * i0;
                unsigned int i1 = (k1 * 3856u) >> 16, g1 = k1 - 17u * i1;
                float v0 = fmaxf(0.0f, 1.0f - fabsf(s_u[i0] - (float)g0));
                float v1 = fmaxf(0.0f, 1.0f - fabsf(s_u[i1] - (float)g1));
                dst[idx] = (unsigned int)f2bf(v0) | ((unsigned int)f2bf(v1) << 16);
            }
        }
    } else {
        const int rb = (blk - 2372 - BATCH) * GM_ROWS;
        #pragma unroll
        for (int j = tid; j < GM_ROWS * NI; j += 256) {
            float xv = x[(size_t)rb * NI + j];
            s_sil[j] = xv / (1.0f + __expf(-xv));
        }
        __syncthreads();
        float acc[GM_ROWS] = {};
        const int o = tid;
        #pragma unroll 4
        for (int k = 0; k < NI; ++k) {
            float bv = bs0[(size_t)k * NH + o];
            #pragma unroll
            for (int r = 0; r < GM_ROWS; ++r)
                acc[r] += s_sil[r * NI + k] * bv;
        }
        #pragma unroll
        for (int r = 0; r < GM_ROWS; ++r)
            hbase[(size_t)(rb + r) * NH + o] = acc[r];
    }
}

// ---- spline GEMM (bf16 MFMA, A from memory): hbase += basisA @ w0 ----
// Layouts/conventions identical to r14's validated kernel; A now a 16-B load.
__global__ __launch_bounds__(256) void spline_gemm(
    const unsigned short* __restrict__ basisA,  // (B, K0) bf16 row-major
    const unsigned short* __restrict__ w0B,     // fragment-linear
    float* __restrict__ hsum)                   // in: base; out: base + spline
{
    const int bm   = blockIdx.x & 255;    // M-tile (16 rows)
    const int bn   = blockIdx.x >> 8;     // 0..3 (64-o group)
    const int tid  = threadIdx.x;
    const int lane = tid & 63;
    const int wave = tid >> 6;            // 0..3
    const int r    = lane & 15;
    const int kg   = lane >> 4;           // 0..3
    const int o    = bn * 64 + wave * 16 + r;

    const unsigned short* arow  = basisA + (size_t)(bm * 16 + r) * K0 + kg * 8;
    const unsigned short* bbase = w0B + (size_t)o * 32 + kg * 8;
    f32x4 acc = {0.f, 0.f, 0.f, 0.f};
    #pragma unroll 4
    for (int kt = 0; kt < 68; ++kt) {
        const bf16x8 av = *reinterpret_cast<const bf16x8*>(arow + kt * 32);
        const bf16x8 bv = *reinterpret_cast<const bf16x8*>(bbase + (size_t)kt * 8192);
        acc = __builtin_amdgcn_mfma_f32_16x16x32_bf16(av, bv, acc, 0, 0, 0);
    }
    // D: row = kg*4+reg (within tile), col = o; accumulate onto base (disjoint ownership)
    #pragma unroll
    for (int reg = 0; reg < 4; ++reg) {
        const size_t idx = (size_t)(bm * 16 + kg * 4 + reg) * NH + o;
        hsum[idx] += acc[reg];
    }
}

// ---- fused LN -> KAN layer-1: one 128-thread block per row (no L0 phase) ----
__global__ __launch_bounds__(128) void kan_fused(
    const float* __restrict__ hsum,         // (B, NH) = base + spline (pre-scale)
    const float* __restrict__ bias0,
    const unsigned short* __restrict__ bs1, // bf16 (H,NO)
    const float* __restrict__ bias1,
    const float* __restrict__ gamma,
    const float* __restrict__ beta,
    const unsigned short* __restrict__ w1t, // bf16 (H,G,NO)
    float* __restrict__ out,
    float4* __restrict__ partials)
{
    __shared__ float s_sil1[NH], s_wlo1[NH], s_whi1[NH], s_u1[NH];
    __shared__ int   s_glo1[NH], s_ghi1[NH];
    __shared__ float2 s_ln[2];
    __shared__ float4 s_out4[128];
    __shared__ float4 s_red4[128];

    const int tid = threadIdx.x;      // 0..127
    const int b   = blockIdx.x;

    // ---- h for o-pair (2t, 2t+1) ----
    const int op = tid * 2;
    float h0, h1;
    {
        const float2 hs = *reinterpret_cast<const float2*>(hsum + (size_t)b * NH + op);
        const float2 b0 = *reinterpret_cast<const float2*>(bias0 + op);
        h0 = hs.x * 0.08838834764831844f + b0.x;   // 1/sqrt(128)
        h1 = hs.y * 0.08838834764831844f + b0.y;
    }

    // ---- LayerNorm over 256: wave shfl butterfly + 2-wave combine ----
    {
        float s = h0 + h1, q = h0 * h0 + h1 * h1;
        #pragma unroll
        for (int d = 1; d < 64; d <<= 1) {
            s += __shfl_xor(s, d, 64);
            q += __shfl_xor(q, d, 64);
        }
        if ((tid & 63) == 0) s_ln[tid >> 6] = make_float2(s, q);
    }
    __syncthreads();
    float hn0, hn1;
    {
        const float2 a = s_ln[0], c = s_ln[1];
        const float mu = (a.x + c.x) * (1.0f / NH);
        const float ms = (a.y + c.y) * (1.0f / NH);
        const float rs = rsqrtf(ms - mu * mu + 1e-5f);
        const float2 gm = *reinterpret_cast<const float2*>(gamma + op);
        const float2 bt = *reinterpret_cast<const float2*>(beta + op);
        hn0 = (h0 - mu) * rs * gm.x + bt.x;
        hn1 = (h1 - mu) * rs * gm.y + bt.y;
    }

    // ---- layer-1 taps for i = 2t, 2t+1 ----
    float bsum, bsq;
    {
        float sil, wlo, whi, u; int glo, ghi;
        taps(hn0, sil, wlo, whi, glo, ghi, u);
        s_sil1[op] = sil; s_wlo1[op] = wlo; s_whi1[op] = whi;
        s_glo1[op] = glo; s_ghi1[op] = ghi; s_u1[op] = u;
        bsum = wlo + whi;  bsq = wlo * wlo + whi * whi;
        taps(hn1, sil, wlo, whi, glo, ghi, u);
        s_sil1[op + 1] = sil; s_wlo1[op + 1] = wlo; s_whi1[op + 1] = whi;
        s_glo1[op + 1] = glo; s_ghi1[op + 1] = ghi; s_u1[op + 1] = u;
        bsum += wlo + whi; bsq += wlo * wlo + whi * whi;
    }
    __syncthreads();

    // ---- basis1: 256*17 = 4352 floats = 2176 float2, nontemporal ----
    {
        float* bo = out + BASIS_OFF + (size_t)b * (NH * NG);
        #pragma unroll
        for (int it = 0; it < 17; ++it) {
            int f0 = (it * 128 + tid) * 2;
            int i0 = f0 / NG,       g0 = f0 - i0 * NG;
            int i1 = (f0 + 1) / NG, g1 = (f0 + 1) - i1 * NG;
            vf2 v;
            v.x = fmaxf(0.0f, 1.0f - fabsf(s_u1[i0] - (float)g0));
            v.y = fmaxf(0.0f, 1.0f - fabsf(s_u1[i1] - (float)g1));
            __builtin_nontemporal_store(v, reinterpret_cast<vf2*>(bo + f0));
        }
    }

    // ---- layer-1 edge loop: thread owns o-quad po..po+3, quarter of the i-range ----
    const int po = (tid & 31) * 4;
    const int q  = tid >> 5;            // i-quarter 0..3
    float4 osum = make_float4(0.f, 0.f, 0.f, 0.f);
    float esq = 0.0f;
    float* eo = out + EDGE_OFF + (size_t)b * (NH * NO);
    #pragma unroll 4
    for (int it = 0; it < 64; ++it) {
        const int i = q * 64 + it;
        const float sil = s_sil1[i], wlo = s_wlo1[i], whi = s_whi1[i];
        const float4 bsv = bf4_to_f4(*reinterpret_cast<const uint2*>(bs1 + (size_t)i * NO + po));
        const float4 wl  = bf4_to_f4(*reinterpret_cast<const uint2*>(w1t + (size_t)(i * NG + s_glo1[i]) * NO + po));
        const float4 wh  = bf4_to_f4(*reinterpret_cast<const uint2*>(w1t + (size_t)(i * NG + s_ghi1[i]) * NO + po));
        vf4 e;
        e.x = sil * bsv.x + wlo * wl.x + whi * wh.x;
        e.y = sil * bsv.y + wlo * wl.y + whi * wh.y;
        e.z = sil * bsv.z + wlo * wl.z + whi * wh.z;
        e.w = sil * bsv.w + wlo * wl.w + whi * wh.w;
        __builtin_nontemporal_store(e, reinterpret_cast<vf4*>(eo + (size_t)i * NO + po));
        osum.x += e.x; osum.y += e.y; osum.z += e.z; osum.w += e.w;
        esq += e.x * e.x + e.y * e.y + e.z * e.z + e.w * e.w;
    }

    // ---- out row: combine the 4 i-quarters per o-quad ----
    s_out4[tid] = osum;
    __syncthreads();
    if (tid < 32) {
        float4 a = s_out4[tid], b2 = s_out4[tid + 32], c = s_out4[tid + 64], d2 = s_out4[tid + 96];
        const float4 bi = *reinterpret_cast<const float4*>(bias1 + tid * 4);
        float4 o4;
        o4.x = (a.x + b2.x + c.x + d2.x) * 0.0625f + bi.x;   // 1/sqrt(256)
        o4.y = (a.y + b2.y + c.y + d2.y) * 0.0625f + bi.y;
        o4.z = (a.z + b2.z + c.z + d2.z) * 0.0625f + bi.z;
        o4.w = (a.w + b2.w + c.w + d2.w) * 0.0625f + bi.w;
        *reinterpret_cast<float4*>(out + (size_t)b * NO + tid * 4) = o4;
    }

    // ---- diagnostics block reduce ----
    s_red4[tid] = make_float4(osum.x + osum.y + osum.z + osum.w, esq, bsum, bsq);
    __syncthreads();
    for (int s = 64; s > 0; s >>= 1) {
        if (tid < s) {
            float4 a = s_red4[tid], c = s_red4[tid + s];
            s_red4[tid] = make_float4(a.x + c.x, a.y + c.y, a.z + c.z, a.w + c.w);
        }
        __syncthreads();
    }
    if (tid == 0) partials[b] = s_red4[0];
}

// ---- deterministic final reduction of diagnostics ----
__global__ __launch_bounds__(256) void finalize(const float4* __restrict__ partials,
                                                float* __restrict__ out) {
    __shared__ double red[256];
    const int tid = threadIdx.x;
    double a0 = 0, a1 = 0, a2 = 0, a3 = 0;
    for (int j = tid; j < BATCH; j += 256) {
        float4 p = partials[j];
        a0 += (double)p.x; a1 += (double)p.y; a2 += (double)p.z; a3 += (double)p.w;
    }
    double tot[4];
    double v[4] = {a0, a1, a2, a3};
    for (int c = 0; c < 4; ++c) {
        red[tid] = v[c];
        __syncthreads();
        for (int s = 128; s > 0; s >>= 1) {
            if (tid < s) red[tid] += red[tid + s];
            __syncthreads();
        }
        tot[c] = red[0];
        __syncthreads();
    }
    if (tid == 0) {
        const double Ne = (double)BATCH * NH * NO;
        const double Nb = (double)BATCH * NH * NG;
        double me = tot[0] / Ne;
        double ve = tot[1] / Ne - me * me;
        double mb = tot[2] / Nb;
        double vb = tot[3] / Nb - mb * mb;
        out[SCAL_OFF + 0] = (float)me;
        out[SCAL_OFF + 1] = (float)sqrt(ve > 0.0 ? ve : 0.0);
        out[SCAL_OFF + 2] = (float)mb;
        out[SCAL_OFF + 3] = (float)sqrt(vb > 0.0 ? vb : 0.0);
    }
}

extern "C" void kernel_launch(void* const* d_in, const int* in_sizes, int n_in,
                              void* d_out, int out_size, void* d_ws, size_t ws_size,
                              hipStream_t stream) {
    const float* x     = (const float*)d_in[0];
    const float* bs0   = (const float*)d_in[1];
    const float* w0    = (const float*)d_in[2];
    const float* bias0 = (const float*)d_in[3];
    const float* bs1   = (const float*)d_in[4];
    const float* w1    = (const float*)d_in[5];
    const float* bias1 = (const float*)d_in[6];
    const float* gamma = (const float*)d_in[7];
    const float* beta  = (const float*)d_in[8];
    float* out = (float*)d_out;

    unsigned short* w0B  = (unsigned short*)d_ws;                 // 557056 bf16
    unsigned short* w1t  = w0B + (size_t)68 * 8192;               // 557056 bf16
    unsigned short* bs1b = w1t + (size_t)NH * NG * NO;            // 32768 bf16
    size_t ofs = ((size_t)(68 * 8192) + (size_t)(NH * NG * NO) + NH * NO) * sizeof(unsigned short);
    ofs = (ofs + 15) & ~(size_t)15;
    float4*       partials = (float4*)((char*)d_ws + ofs);        // 64 KB
    float*        hsum     = (float*)((char*)d_ws + ofs + BATCH * sizeof(float4));  // 4 MB
    unsigned int* basisA   = (unsigned int*)(hsum + (size_t)BATCH * NH);            // 17.8 MB

    hipLaunchKernelGGL(prep_all, dim3(2372 + BATCH + BATCH / GM_ROWS), dim3(256), 0, stream,
                       x, w0, w1, bs1, bs0, w0B, w1t, bs1b, basisA, hsum);
    hipLaunchKernelGGL(spline_gemm, dim3(1024), dim3(256), 0, stream,
                       (const unsigned short*)basisA, w0B, hsum);
    hipLaunchKernelGGL(kan_fused, dim3(BATCH), dim3(128), 0, stream,
                       hsum, bias0, bs1b, bias1, gamma, beta, w1t, out, partials);
    hipLaunchKernelGGL(finalize, dim3(1), dim3(256), 0, stream, partials, out);
}

// Round 17
// 152.695 us; speedup vs baseline: 1.1833x; 1.1833x over previous
//
#include <hip/hip_runtime.h>

#define BATCH 4096
#define NI 128
#define NH 256
#define NO 128
#define NG 17
#define GM_ROWS 8

static constexpr size_t EDGE_OFF  = (size_t)BATCH * NO;                    // 524288
static constexpr size_t BASIS_OFF = EDGE_OFF + (size_t)BATCH * NH * NO;    // 134742016
static constexpr size_t SCAL_OFF  = BASIS_OFF + (size_t)BATCH * NH * NG;   // 152567808

typedef float  vf2 __attribute__((ext_vector_type(2)));
typedef float  vf4 __attribute__((ext_vector_type(4)));

__device__ __forceinline__ unsigned short f2bf(float v) {
    unsigned int b = __float_as_uint(v);
    b += 0x7FFFu + ((b >> 16) & 1u);
    return (unsigned short)(b >> 16);
}
__device__ __forceinline__ float2 bf2_to_f2(unsigned int v) {
    float2 r;
    r.x = __uint_as_float(v << 16);
    r.y = __uint_as_float(v & 0xFFFF0000u);
    return r;
}
__device__ __forceinline__ float4 bf4_to_f4(uint2 v) {
    float4 r;
    r.x = __uint_as_float(v.x << 16);
    r.y = __uint_as_float(v.x & 0xFFFF0000u);
    r.z = __uint_as_float(v.y << 16);
    r.w = __uint_as_float(v.y & 0xFFFF0000u);
    return r;
}

// degree-1 hat-spline taps at grid linspace(-2.5,2.5,17), spacing 0.3125
__device__ __forceinline__ void taps(float v, float& sil, float& wlo, float& whi,
                                     int& glo, int& ghi, float& u) {
    sil = v / (1.0f + __expf(-v));
    u   = (v + 2.5f) * 3.2f;
    float kf = floorf(u);
    int   k  = (int)kf;
    float f  = u - kf;
    wlo = 1.0f - f;  whi = f;
    glo = k;         ghi = k + 1;
    if (glo < 0 || glo > 16) { glo = 0; wlo = 0.0f; }
    if (ghi < 0 || ghi > 16) { ghi = 0; whi = 0.0f; }
}

// ---- prep (single launch): blocks [0,4480) transpose/convert; [4480,4992) base GEMM ----
__global__ __launch_bounds__(256) void prep(
    const float* __restrict__ x,
    const float* __restrict__ w0, const float* __restrict__ w1,
    const float* __restrict__ bs1, const float* __restrict__ bs0,
    unsigned short* __restrict__ w0t, unsigned short* __restrict__ w1t,
    unsigned short* __restrict__ bs1b, float* __restrict__ hbase)
{
    __shared__ float s_sil[GM_ROWS * NI];   // 4 KB (base_gemm branch only)
    const int blk = blockIdx.x;
    const int tid = threadIdx.x;

    if (blk < 4480) {
        int j = blk * 256 + tid;
        const int total0 = NI * NG * NH;  // 557056
        const int total1 = NH * NG * NO;  // 557056
        if (j < total0) {
            int i = j / (NG * NH);
            int r = j - i * (NG * NH);
            int g = r / NH;
            int o = r - g * NH;
            w0t[j] = f2bf(w0[((size_t)i * NH + o) * NG + g]);
        } else if (j < total0 + total1) {
            int jj = j - total0;
            int i = jj / (NG * NO);
            int r = jj - i * (NG * NO);
            int g = r / NO;
            int o = r - g * NO;
            w1t[jj] = f2bf(w1[((size_t)i * NO + o) * NG + g]);
        } else if (j < total0 + total1 + NH * NO) {
            int jj = j - total0 - total1;   // 0..32767
            bs1b[jj] = f2bf(bs1[jj]);
        }
    } else {
        const int rb = (blk - 4480) * GM_ROWS;
        #pragma unroll
        for (int j = tid; j < GM_ROWS * NI; j += 256) {
            float xv = x[(size_t)rb * NI + j];
            s_sil[j] = xv / (1.0f + __expf(-xv));
        }
        __syncthreads();
        float acc[GM_ROWS] = {};
        const int o = tid;
        #pragma unroll 4
        for (int k = 0; k < NI; ++k) {
            float bv = bs0[(size_t)k * NH + o];
            #pragma unroll
            for (int r = 0; r < GM_ROWS; ++r)
                acc[r] += s_sil[r * NI + k] * bv;
        }
        #pragma unroll
        for (int r = 0; r < GM_ROWS; ++r)
            hbase[(size_t)(rb + r) * NH + o] = acc[r];
    }
}

// ---- fused KAN -> LN -> KAN: one 128-thread block per row (r15 winner) ----
__global__ __launch_bounds__(128) void kan_fused(
    const float* __restrict__ x,
    const float* __restrict__ hbase,        // fp32 (B, NH) from prep
    const float* __restrict__ bias0,
    const unsigned short* __restrict__ bs1, // bf16 (H,NO)
    const float* __restrict__ bias1,
    const float* __restrict__ gamma,
    const float* __restrict__ beta,
    const unsigned short* __restrict__ w0t, // bf16 (I,G,NH)
    const unsigned short* __restrict__ w1t, // bf16 (H,G,NO)
    float* __restrict__ out,
    float4* __restrict__ partials)
{
    __shared__ float s_wlo0[NI], s_whi0[NI];
    __shared__ int   s_gp0[NI];
    __shared__ float s_sil1[NH], s_wlo1[NH], s_whi1[NH], s_u1[NH];
    __shared__ int   s_glo1[NH], s_ghi1[NH];
    __shared__ float2 s_ln[2];
    __shared__ float4 s_out4[128];
    __shared__ float4 s_red4[128];

    const int tid = threadIdx.x;      // 0..127
    const int b   = blockIdx.x;

    // ---- layer-0 taps, i = tid (silu hoisted to prep/base_gemm) ----
    {
        float xv = x[(size_t)b * NI + tid];
        float sil, wlo, whi, u; int glo, ghi;
        taps(xv, sil, wlo, whi, glo, ghi, u);
        s_wlo0[tid] = wlo; s_whi0[tid] = whi;
        s_gp0[tid] = glo | (ghi << 8);
    }
    __syncthreads();

    // ---- spline part of h for o-pair (2t, 2t+1) ----
    const int op = tid * 2;
    float h0 = 0.0f, h1 = 0.0f;
    #pragma unroll 8
    for (int i = 0; i < NI; ++i) {
        const float wlo = s_wlo0[i], whi = s_whi0[i];
        const unsigned int gp = (unsigned int)s_gp0[i];
        const float2 wl = bf2_to_f2(*reinterpret_cast<const unsigned int*>(w0t + ((size_t)i * NG + (gp & 0xffu)) * NH + op));
        const float2 wh = bf2_to_f2(*reinterpret_cast<const unsigned int*>(w0t + ((size_t)i * NG + (gp >> 8)) * NH + op));
        h0 += wlo * wl.x + whi * wh.x;
        h1 += wlo * wl.y + whi * wh.y;
    }
    {
        const float2 hb = *reinterpret_cast<const float2*>(hbase + (size_t)b * NH + op);
        const float2 b0 = *reinterpret_cast<const float2*>(bias0 + op);
        h0 = (h0 + hb.x) * 0.08838834764831844f + b0.x;   // 1/sqrt(128)
        h1 = (h1 + hb.y) * 0.08838834764831844f + b0.y;
    }

    // ---- LayerNorm over 256: wave shfl butterfly + 2-wave combine ----
    {
        float s = h0 + h1, q = h0 * h0 + h1 * h1;
        #pragma unroll
        for (int d = 1; d < 64; d <<= 1) {
            s += __shfl_xor(s, d, 64);
            q += __shfl_xor(q, d, 64);
        }
        if ((tid & 63) == 0) s_ln[tid >> 6] = make_float2(s, q);
    }
    __syncthreads();
    float hn0, hn1;
    {
        const float2 a = s_ln[0], c = s_ln[1];
        const float mu = (a.x + c.x) * (1.0f / NH);
        const float ms = (a.y + c.y) * (1.0f / NH);
        const float rs = rsqrtf(ms - mu * mu + 1e-5f);
        const float2 gm = *reinterpret_cast<const float2*>(gamma + op);
        const float2 bt = *reinterpret_cast<const float2*>(beta + op);
        hn0 = (h0 - mu) * rs * gm.x + bt.x;
        hn1 = (h1 - mu) * rs * gm.y + bt.y;
    }

    // ---- layer-1 taps for i = 2t, 2t+1 ----
    float bsum, bsq;
    {
        float sil, wlo, whi, u; int glo, ghi;
        taps(hn0, sil, wlo, whi, glo, ghi, u);
        s_sil1[op] = sil; s_wlo1[op] = wlo; s_whi1[op] = whi;
        s_glo1[op] = glo; s_ghi1[op] = ghi; s_u1[op] = u;
        bsum = wlo + whi;  bsq = wlo * wlo + whi * whi;
        taps(hn1, sil, wlo, whi, glo, ghi, u);
        s_sil1[op + 1] = sil; s_wlo1[op + 1] = wlo; s_whi1[op + 1] = whi;
        s_glo1[op + 1] = glo; s_ghi1[op + 1] = ghi; s_u1[op + 1] = u;
        bsum += wlo + whi; bsq += wlo * wlo + whi * whi;
    }
    __syncthreads();

    // ---- basis1: 256*17 = 4352 floats = 2176 float2, nontemporal ----
    {
        float* bo = out + BASIS_OFF + (size_t)b * (NH * NG);
        #pragma unroll
        for (int it = 0; it < 17; ++it) {
            int f0 = (it * 128 + tid) * 2;
            int i0 = f0 / NG,       g0 = f0 - i0 * NG;
            int i1 = (f0 + 1) / NG, g1 = (f0 + 1) - i1 * NG;
            vf2 v;
            v.x = fmaxf(0.0f, 1.0f - fabsf(s_u1[i0] - (float)g0));
            v.y = fmaxf(0.0f, 1.0f - fabsf(s_u1[i1] - (float)g1));
            __builtin_nontemporal_store(v, reinterpret_cast<vf2*>(bo + f0));
        }
    }

    // ---- layer-1 edge loop: thread owns o-quad po..po+3, quarter of the i-range ----
    const int po = (tid & 31) * 4;
    const int q  = tid >> 5;            // i-quarter 0..3
    float4 osum = make_float4(0.f, 0.f, 0.f, 0.f);
    float esq = 0.0f;
    float* eo = out + EDGE_OFF + (size_t)b * (NH * NO);
    #pragma unroll 4
    for (int it = 0; it < 64; ++it) {
        const int i = q * 64 + it;
        const float sil = s_sil1[i], wlo = s_wlo1[i], whi = s_whi1[i];
        const float4 bsv = bf4_to_f4(*reinterpret_cast<const uint2*>(bs1 + (size_t)i * NO + po));
        const float4 wl  = bf4_to_f4(*reinterpret_cast<const uint2*>(w1t + (size_t)(i * NG + s_glo1[i]) * NO + po));
        const float4 wh  = bf4_to_f4(*reinterpret_cast<const uint2*>(w1t + (size_t)(i * NG + s_ghi1[i]) * NO + po));
        vf4 e;
        e.x = sil * bsv.x + wlo * wl.x + whi * wh.x;
        e.y = sil * bsv.y + wlo * wl.y + whi * wh.y;
        e.z = sil * bsv.z + wlo * wl.z + whi * wh.z;
        e.w = sil * bsv.w + wlo * wl.w + whi * wh.w;
        __builtin_nontemporal_store(e, reinterpret_cast<vf4*>(eo + (size_t)i * NO + po));
        osum.x += e.x; osum.y += e.y; osum.z += e.z; osum.w += e.w;
        esq += e.x * e.x + e.y * e.y + e.z * e.z + e.w * e.w;
    }

    // ---- out row: combine the 4 i-quarters per o-quad ----
    s_out4[tid] = osum;
    __syncthreads();
    if (tid < 32) {
        float4 a = s_out4[tid], b2 = s_out4[tid + 32], c = s_out4[tid + 64], d2 = s_out4[tid + 96];
        const float4 bi = *reinterpret_cast<const float4*>(bias1 + tid * 4);
        float4 o4;
        o4.x = (a.x + b2.x + c.x + d2.x) * 0.0625f + bi.x;   // 1/sqrt(256)
        o4.y = (a.y + b2.y + c.y + d2.y) * 0.0625f + bi.y;
        o4.z = (a.z + b2.z + c.z + d2.z) * 0.0625f + bi.z;
        o4.w = (a.w + b2.w + c.w + d2.w) * 0.0625f + bi.w;
        *reinterpret_cast<float4*>(out + (size_t)b * NO + tid * 4) = o4;
    }

    // ---- diagnostics block reduce ----
    s_red4[tid] = make_float4(osum.x + osum.y + osum.z + osum.w, esq, bsum, bsq);
    __syncthreads();
    for (int s = 64; s > 0; s >>= 1) {
        if (tid < s) {
            float4 a = s_red4[tid], c = s_red4[tid + s];
            s_red4[tid] = make_float4(a.x + c.x, a.y + c.y, a.z + c.z, a.w + c.w);
        }
        __syncthreads();
    }
    if (tid == 0) partials[b] = s_red4[0];
}

// ---- deterministic final reduction of diagnostics ----
__global__ __launch_bounds__(256) void finalize(const float4* __restrict__ partials,
                                                float* __restrict__ out) {
    __shared__ double red[256];
    const int tid = threadIdx.x;
    double a0 = 0, a1 = 0, a2 = 0, a3 = 0;
    for (int j = tid; j < BATCH; j += 256) {
        float4 p = partials[j];
        a0 += (double)p.x; a1 += (double)p.y; a2 += (double)p.z; a3 += (double)p.w;
    }
    double tot[4];
    double v[4] = {a0, a1, a2, a3};
    for (int c = 0; c < 4; ++c) {
        red[tid] = v[c];
        __syncthreads();
        for (int s = 128; s > 0; s >>= 1) {
            if (tid < s) red[tid] += red[tid + s];
            __syncthreads();
        }
        tot[c] = red[0];
        __syncthreads();
    }
    if (tid == 0) {
        const double Ne = (double)BATCH * NH * NO;
        const double Nb = (double)BATCH * NH * NG;
        double me = tot[0] / Ne;
        double ve = tot[1] / Ne - me * me;
        double mb = tot[2] / Nb;
        double vb = tot[3] / Nb - mb * mb;
        out[SCAL_OFF + 0] = (float)me;
        out[SCAL_OFF + 1] = (float)sqrt(ve > 0.0 ? ve : 0.0);
        out[SCAL_OFF + 2] = (float)mb;
        out[SCAL_OFF + 3] = (float)sqrt(vb > 0.0 ? vb : 0.0);
    }
}

extern "C" void kernel_launch(void* const* d_in, const int* in_sizes, int n_in,
                              void* d_out, int out_size, void* d_ws, size_t ws_size,
                              hipStream_t stream) {
    const float* x     = (const float*)d_in[0];
    const float* bs0   = (const float*)d_in[1];
    const float* w0    = (const float*)d_in[2];
    const float* bias0 = (const float*)d_in[3];
    const float* bs1   = (const float*)d_in[4];
    const float* w1    = (const float*)d_in[5];
    const float* bias1 = (const float*)d_in[6];
    const float* gamma = (const float*)d_in[7];
    const float* beta  = (const float*)d_in[8];
    float* out = (float*)d_out;

    unsigned short* w0t  = (unsigned short*)d_ws;                 // 557056 bf16
    unsigned short* w1t  = w0t + (size_t)NI * NG * NH;            // 557056 bf16
    unsigned short* bs1b = w1t + (size_t)NH * NG * NO;            // 32768 bf16
    size_t ofs = ((size_t)(NI * NG * NH) + (size_t)(NH * NG * NO) + NH * NO) * sizeof(unsigned short);
    ofs = (ofs + 15) & ~(size_t)15;
    float4* partials = (float4*)((char*)d_ws + ofs);              // 4096 float4
    float*  hbase    = (float*)((char*)d_ws + ofs + BATCH * sizeof(float4));  // 4 MB

    hipLaunchKernelGGL(prep, dim3(4480 + BATCH / GM_ROWS), dim3(256), 0, stream,
                       x, w0, w1, bs1, bs0, w0t, w1t, bs1b, hbase);
    hipLaunchKernelGGL(kan_fused, dim3(BATCH), dim3(128), 0, stream,
                       x, hbase, bias0, bs1b, bias1, gamma, beta, w0t, w1t, out, partials);
    hipLaunchKernelGGL(finalize, dim3(1), dim3(256), 0, stream, partials, out);
}

// Round 18
// 147.748 us; speedup vs baseline: 1.2230x; 1.0335x over previous
//
#include <hip/hip_runtime.h>

#define BATCH 4096
#define NI 128
#define NH 256
#define NO 128
#define NG 17
#define GM_ROWS 8

static constexpr size_t EDGE_OFF  = (size_t)BATCH * NO;                    // 524288
static constexpr size_t BASIS_OFF = EDGE_OFF + (size_t)BATCH * NH * NO;    // 134742016
static constexpr size_t SCAL_OFF  = BASIS_OFF + (size_t)BATCH * NH * NG;   // 152567808

typedef float  vf2 __attribute__((ext_vector_type(2)));
typedef float  vf4 __attribute__((ext_vector_type(4)));

__device__ __forceinline__ unsigned short f2bf(float v) {
    unsigned int b = __float_as_uint(v);
    b += 0x7FFFu + ((b >> 16) & 1u);
    return (unsigned short)(b >> 16);
}
__device__ __forceinline__ float2 bf2_to_f2(unsigned int v) {
    float2 r;
    r.x = __uint_as_float(v << 16);
    r.y = __uint_as_float(v & 0xFFFF0000u);
    return r;
}
__device__ __forceinline__ float4 bf4_to_f4(uint2 v) {
    float4 r;
    r.x = __uint_as_float(v.x << 16);
    r.y = __uint_as_float(v.x & 0xFFFF0000u);
    r.z = __uint_as_float(v.y << 16);
    r.w = __uint_as_float(v.y & 0xFFFF0000u);
    return r;
}

// degree-1 hat-spline taps at grid linspace(-2.5,2.5,17), spacing 0.3125
__device__ __forceinline__ void taps(float v, float& sil, float& wlo, float& whi,
                                     int& glo, int& ghi, float& u) {
    sil = v / (1.0f + __expf(-v));
    u   = (v + 2.5f) * 3.2f;
    float kf = floorf(u);
    int   k  = (int)kf;
    float f  = u - kf;
    wlo = 1.0f - f;  whi = f;
    glo = k;         ghi = k + 1;
    if (glo < 0 || glo > 16) { glo = 0; wlo = 0.0f; }
    if (ghi < 0 || ghi > 16) { ghi = 0; whi = 0.0f; }
}

// ---- transpose (I,O,G)->(I,G,O) + bf16 convert; bs1 -> bf16 (bs0 stays fp32) ----
__global__ __launch_bounds__(256) void transpose_convert(
    const float* __restrict__ w0, const float* __restrict__ w1,
    const float* __restrict__ bs1,
    unsigned short* __restrict__ w0t, unsigned short* __restrict__ w1t,
    unsigned short* __restrict__ bs1b) {
    int j = blockIdx.x * 256 + threadIdx.x;
    const int total0 = NI * NG * NH;  // 557056
    const int total1 = NH * NG * NO;  // 557056
    if (j < total0) {
        int i = j / (NG * NH);
        int r = j - i * (NG * NH);
        int g = r / NH;
        int o = r - g * NH;
        w0t[j] = f2bf(w0[((size_t)i * NH + o) * NG + g]);
    } else if (j < total0 + total1) {
        int jj = j - total0;
        int i = jj / (NG * NO);
        int r = jj - i * (NG * NO);
        int g = r / NO;
        int o = r - g * NO;
        w1t[jj] = f2bf(w1[((size_t)i * NO + o) * NG + g]);
    } else {
        int jj = j - total0 - total1;   // 0..32767
        bs1b[jj] = f2bf(bs1[jj]);
    }
}

// ---- base GEMM: hbase[b][o] = sum_i silu(x[b][i]) * bs0[i][o], pure fp32 ----
__global__ __launch_bounds__(256) void base_gemm(
    const float* __restrict__ x,      // (B, NI)
    const float* __restrict__ bs0,    // (NI, NH) fp32
    float* __restrict__ hbase)        // (B, NH)
{
    __shared__ float s_sil[GM_ROWS * NI];   // 4 KB
    const int tid = threadIdx.x;
    const int rb  = blockIdx.x * GM_ROWS;

    #pragma unroll
    for (int j = tid; j < GM_ROWS * NI; j += 256) {
        float xv = x[(size_t)rb * NI + j];
        s_sil[j] = xv / (1.0f + __expf(-xv));
    }
    __syncthreads();

    float acc[GM_ROWS] = {};
    const int o = tid;
    #pragma unroll 4
    for (int k = 0; k < NI; ++k) {
        float bv = bs0[(size_t)k * NH + o];
        #pragma unroll
        for (int r = 0; r < GM_ROWS; ++r)
            acc[r] += s_sil[r * NI + k] * bv;
    }
    #pragma unroll
    for (int r = 0; r < GM_ROWS; ++r)
        hbase[(size_t)(rb + r) * NH + o] = acc[r];
}

// ---- fused KAN -> LN -> KAN: one 128-thread block per row (r15 winner) ----
__global__ __launch_bounds__(128) void kan_fused(
    const float* __restrict__ x,
    const float* __restrict__ hbase,        // fp32 (B, NH) from base_gemm
    const float* __restrict__ bias0,
    const unsigned short* __restrict__ bs1, // bf16 (H,NO)
    const float* __restrict__ bias1,
    const float* __restrict__ gamma,
    const float* __restrict__ beta,
    const unsigned short* __restrict__ w0t, // bf16 (I,G,NH)
    const unsigned short* __restrict__ w1t, // bf16 (H,G,NO)
    float* __restrict__ out,
    float4* __restrict__ partials)
{
    __shared__ float s_wlo0[NI], s_whi0[NI];
    __shared__ int   s_gp0[NI];
    __shared__ float s_sil1[NH], s_wlo1[NH], s_whi1[NH], s_u1[NH];
    __shared__ int   s_glo1[NH], s_ghi1[NH];
    __shared__ float2 s_ln[2];
    __shared__ float4 s_out4[128];
    __shared__ float4 s_red4[128];

    const int tid = threadIdx.x;      // 0..127
    const int b   = blockIdx.x;

    // ---- layer-0 taps, i = tid (silu hoisted to base_gemm) ----
    {
        float xv = x[(size_t)b * NI + tid];
        float sil, wlo, whi, u; int glo, ghi;
        taps(xv, sil, wlo, whi, glo, ghi, u);
        s_wlo0[tid] = wlo; s_whi0[tid] = whi;
        s_gp0[tid] = glo | (ghi << 8);
    }
    __syncthreads();

    // ---- spline part of h for o-pair (2t, 2t+1) ----
    const int op = tid * 2;
    float h0 = 0.0f, h1 = 0.0f;
    #pragma unroll 8
    for (int i = 0; i < NI; ++i) {
        const float wlo = s_wlo0[i], whi = s_whi0[i];
        const unsigned int gp = (unsigned int)s_gp0[i];
        const float2 wl = bf2_to_f2(*reinterpret_cast<const unsigned int*>(w0t + ((size_t)i * NG + (gp & 0xffu)) * NH + op));
        const float2 wh = bf2_to_f2(*reinterpret_cast<const unsigned int*>(w0t + ((size_t)i * NG + (gp >> 8)) * NH + op));
        h0 += wlo * wl.x + whi * wh.x;
        h1 += wlo * wl.y + whi * wh.y;
    }
    {
        const float2 hb = *reinterpret_cast<const float2*>(hbase + (size_t)b * NH + op);
        const float2 b0 = *reinterpret_cast<const float2*>(bias0 + op);
        h0 = (h0 + hb.x) * 0.08838834764831844f + b0.x;   // 1/sqrt(128)
        h1 = (h1 + hb.y) * 0.08838834764831844f + b0.y;
    }

    // ---- LayerNorm over 256: wave shfl butterfly + 2-wave combine ----
    {
        float s = h0 + h1, q = h0 * h0 + h1 * h1;
        #pragma unroll
        for (int d = 1; d < 64; d <<= 1) {
            s += __shfl_xor(s, d, 64);
            q += __shfl_xor(q, d, 64);
        }
        if ((tid & 63) == 0) s_ln[tid >> 6] = make_float2(s, q);
    }
    __syncthreads();
    float hn0, hn1;
    {
        const float2 a = s_ln[0], c = s_ln[1];
        const float mu = (a.x + c.x) * (1.0f / NH);
        const float ms = (a.y + c.y) * (1.0f / NH);
        const float rs = rsqrtf(ms - mu * mu + 1e-5f);
        const float2 gm = *reinterpret_cast<const float2*>(gamma + op);
        const float2 bt = *reinterpret_cast<const float2*>(beta + op);
        hn0 = (h0 - mu) * rs * gm.x + bt.x;
        hn1 = (h1 - mu) * rs * gm.y + bt.y;
    }

    // ---- layer-1 taps for i = 2t, 2t+1 ----
    float bsum, bsq;
    {
        float sil, wlo, whi, u; int glo, ghi;
        taps(hn0, sil, wlo, whi, glo, ghi, u);
        s_sil1[op] = sil; s_wlo1[op] = wlo; s_whi1[op] = whi;
        s_glo1[op] = glo; s_ghi1[op] = ghi; s_u1[op] = u;
        bsum = wlo + whi;  bsq = wlo * wlo + whi * whi;
        taps(hn1, sil, wlo, whi, glo, ghi, u);
        s_sil1[op + 1] = sil; s_wlo1[op + 1] = wlo; s_whi1[op + 1] = whi;
        s_glo1[op + 1] = glo; s_ghi1[op + 1] = ghi; s_u1[op + 1] = u;
        bsum += wlo + whi; bsq += wlo * wlo + whi * whi;
    }
    __syncthreads();

    // ---- basis1: 256*17 = 4352 floats = 2176 float2, nontemporal ----
    {
        float* bo = out + BASIS_OFF + (size_t)b * (NH * NG);
        #pragma unroll
        for (int it = 0; it < 17; ++it) {
            int f0 = (it * 128 + tid) * 2;
            int i0 = f0 / NG,       g0 = f0 - i0 * NG;
            int i1 = (f0 + 1) / NG, g1 = (f0 + 1) - i1 * NG;
            vf2 v;
            v.x = fmaxf(0.0f, 1.0f - fabsf(s_u1[i0] - (float)g0));
            v.y = fmaxf(0.0f, 1.0f - fabsf(s_u1[i1] - (float)g1));
            __builtin_nontemporal_store(v, reinterpret_cast<vf2*>(bo + f0));
        }
    }

    // ---- layer-1 edge loop: thread owns o-quad po..po+3, quarter of the i-range ----
    const int po = (tid & 31) * 4;
    const int q  = tid >> 5;            // i-quarter 0..3
    float4 osum = make_float4(0.f, 0.f, 0.f, 0.f);
    float esq = 0.0f;
    float* eo = out + EDGE_OFF + (size_t)b * (NH * NO);
    #pragma unroll 4
    for (int it = 0; it < 64; ++it) {
        const int i = q * 64 + it;
        const float sil = s_sil1[i], wlo = s_wlo1[i], whi = s_whi1[i];
        const float4 bsv = bf4_to_f4(*reinterpret_cast<const uint2*>(bs1 + (size_t)i * NO + po));
        const float4 wl  = bf4_to_f4(*reinterpret_cast<const uint2*>(w1t + (size_t)(i * NG + s_glo1[i]) * NO + po));
        const float4 wh  = bf4_to_f4(*reinterpret_cast<const uint2*>(w1t + (size_t)(i * NG + s_ghi1[i]) * NO + po));
        vf4 e;
        e.x = sil * bsv.x + wlo * wl.x + whi * wh.x;
        e.y = sil * bsv.y + wlo * wl.y + whi * wh.y;
        e.z = sil * bsv.z + wlo * wl.z + whi * wh.z;
        e.w = sil * bsv.w + wlo * wl.w + whi * wh.w;
        __builtin_nontemporal_store(e, reinterpret_cast<vf4*>(eo + (size_t)i * NO + po));
        osum.x += e.x; osum.y += e.y; osum.z += e.z; osum.w += e.w;
        esq += e.x * e.x + e.y * e.y + e.z * e.z + e.w * e.w;
    }

    // ---- out row: combine the 4 i-quarters per o-quad ----
    s_out4[tid] = osum;
    __syncthreads();
    if (tid < 32) {
        float4 a = s_out4[tid], b2 = s_out4[tid + 32], c = s_out4[tid + 64], d2 = s_out4[tid + 96];
        const float4 bi = *reinterpret_cast<const float4*>(bias1 + tid * 4);
        float4 o4;
        o4.x = (a.x + b2.x + c.x + d2.x) * 0.0625f + bi.x;   // 1/sqrt(256)
        o4.y = (a.y + b2.y + c.y + d2.y) * 0.0625f + bi.y;
        o4.z = (a.z + b2.z + c.z + d2.z) * 0.0625f + bi.z;
        o4.w = (a.w + b2.w + c.w + d2.w) * 0.0625f + bi.w;
        *reinterpret_cast<float4*>(out + (size_t)b * NO + tid * 4) = o4;
    }

    // ---- diagnostics block reduce ----
    s_red4[tid] = make_float4(osum.x + osum.y + osum.z + osum.w, esq, bsum, bsq);
    __syncthreads();
    for (int s = 64; s > 0; s >>= 1) {
        if (tid < s) {
            float4 a = s_red4[tid], c = s_red4[tid + s];
            s_red4[tid] = make_float4(a.x + c.x, a.y + c.y, a.z + c.z, a.w + c.w);
        }
        __syncthreads();
    }
    if (tid == 0) partials[b] = s_red4[0];
}

// ---- deterministic final reduction of diagnostics ----
__global__ __launch_bounds__(256) void finalize(const float4* __restrict__ partials,
                                                float* __restrict__ out) {
    __shared__ double red[256];
    const int tid = threadIdx.x;
    double a0 = 0, a1 = 0, a2 = 0, a3 = 0;
    for (int j = tid; j < BATCH; j += 256) {
        float4 p = partials[j];
        a0 += (double)p.x; a1 += (double)p.y; a2 += (double)p.z; a3 += (double)p.w;
    }
    double tot[4];
    double v[4] = {a0, a1, a2, a3};
    for (int c = 0; c < 4; ++c) {
        red[tid] = v[c];
        __syncthreads();
        for (int s = 128; s > 0; s >>= 1) {
            if (tid < s) red[tid] += red[tid + s];
            __syncthreads();
        }
        tot[c] = red[0];
        __syncthreads();
    }
    if (tid == 0) {
        const double Ne = (double)BATCH * NH * NO;
        const double Nb = (double)BATCH * NH * NG;
        double me = tot[0] / Ne;
        double ve = tot[1] / Ne - me * me;
        double mb = tot[2] / Nb;
        double vb = tot[3] / Nb - mb * mb;
        out[SCAL_OFF + 0] = (float)me;
        out[SCAL_OFF + 1] = (float)sqrt(ve > 0.0 ? ve : 0.0);
        out[SCAL_OFF + 2] = (float)mb;
        out[SCAL_OFF + 3] = (float)sqrt(vb > 0.0 ? vb : 0.0);
    }
}

extern "C" void kernel_launch(void* const* d_in, const int* in_sizes, int n_in,
                              void* d_out, int out_size, void* d_ws, size_t ws_size,
                              hipStream_t stream) {
    const float* x     = (const float*)d_in[0];
    const float* bs0   = (const float*)d_in[1];
    const float* w0    = (const float*)d_in[2];
    const float* bias0 = (const float*)d_in[3];
    const float* bs1   = (const float*)d_in[4];
    const float* w1    = (const float*)d_in[5];
    const float* bias1 = (const float*)d_in[6];
    const float* gamma = (const float*)d_in[7];
    const float* beta  = (const float*)d_in[8];
    float* out = (float*)d_out;

    unsigned short* w0t  = (unsigned short*)d_ws;                 // 557056 bf16
    unsigned short* w1t  = w0t + (size_t)NI * NG * NH;            // 557056 bf16
    unsigned short* bs1b = w1t + (size_t)NH * NG * NO;            // 32768 bf16
    size_t ofs = ((size_t)(NI * NG * NH) + (size_t)(NH * NG * NO) + NH * NO) * sizeof(unsigned short);
    ofs = (ofs + 15) & ~(size_t)15;
    float4* partials = (float4*)((char*)d_ws + ofs);              // 4096 float4
    float*  hbase    = (float*)((char*)d_ws + ofs + BATCH * sizeof(float4));  // 4 MB

    hipLaunchKernelGGL(transpose_convert, dim3(4480), dim3(256), 0, stream,
                       w0, w1, bs1, w0t, w1t, bs1b);
    hipLaunchKernelGGL(base_gemm, dim3(BATCH / GM_ROWS), dim3(256), 0, stream,
                       x, bs0, hbase);
    hipLaunchKernelGGL(kan_fused, dim3(BATCH), dim3(128), 0, stream,
                       x, hbase, bias0, bs1b, bias1, gamma, beta, w0t, w1t, out, partials);
    hipLaunchKernelGGL(finalize, dim3(1), dim3(256), 0, stream, partials, out);
}